// Round 6
// baseline (296.882 us; speedup 1.0000x reference)
//
#include <hip/hip_runtime.h>
#include <hip/hip_bf16.h>
#include <stdint.h>

// CirculantLinear == dense GEMM: y[b,o] = sum_n x[b,n]*rows[o,n] + bias[o]
// where rows[o,n] = c[o, (4096-n) & 4095].
// M=8192 (B), N=4096 (OUT), K=4096 (IN). fp32 in/out, bf16 MFMA inside.
// R3: T2 swizzle XOR (row>>1)&3 -> conflicts 2.5e7 -> 0.  (248 us GEMM)
// R4: 32x32x16 shape -> REGRESSED (conflicts back) -> reverted.
// R5: dropping lgkm drain -> null (246 us). Phase serialization is the cost.
// R6: 4-slot kstep ring (32KB/slot) + register frag double-buffer:
//     1 barrier per kstep, counted vmcnt(4), MFMA(s) overlaps ds_read(s+1)
//     and stage(s+3). LDS service runs concurrent with the MFMA pipe.

#define B_DIM  8192
#define OUT_DIM 4096
#define IN_DIM  4096

typedef __attribute__((ext_vector_type(8))) short bf16x8;
typedef __attribute__((ext_vector_type(4))) float f32x4;
typedef __attribute__((ext_vector_type(8))) unsigned short u16x8;

__device__ __forceinline__ unsigned short f2bf(float f) {
  unsigned u = __float_as_uint(f);
  return (unsigned short)((u + 0x7fffu + ((u >> 16) & 1u)) >> 16);
}

// ---- fused conversion kernel --------------------------------------------

#define XCHUNKS (B_DIM * IN_DIM / 8 / 256)     // 16384 blocks for x
#define RCHUNKS (OUT_DIM * IN_DIM / 8 / 256)   // 8192 blocks for rows

__global__ void cvt_fused_kernel(const float* __restrict__ x,
                                 const float* __restrict__ c,
                                 unsigned short* __restrict__ xb,
                                 unsigned short* __restrict__ rb) {
  int b = blockIdx.x;
  if (b < XCHUNKS) {
    size_t i = ((size_t)b * 256 + threadIdx.x) * 8;
    const float4* p = (const float4*)(x + i);
    float4 a = p[0];
    float4 q = p[1];
    u16x8 o;
    o[0] = f2bf(a.x); o[1] = f2bf(a.y); o[2] = f2bf(a.z); o[3] = f2bf(a.w);
    o[4] = f2bf(q.x); o[5] = f2bf(q.y); o[6] = f2bf(q.z); o[7] = f2bf(q.w);
    *(u16x8*)(xb + i) = o;
  } else {
    int idx = (b - XCHUNKS) * 256 + threadIdx.x;
    int o  = idx >> 9;
    int n0 = (idx & 511) << 3;
    const float* crow = c + (size_t)o * IN_DIM;
    u16x8 v;
#pragma unroll
    for (int j = 0; j < 8; ++j) {
      int n = n0 + j;
      int s = (IN_DIM - n) & (IN_DIM - 1);
      v[j] = f2bf(crow[s]);
    }
    *(u16x8*)(rb + (size_t)o * IN_DIM + n0) = v;
  }
}

// ---- GEMM ---------------------------------------------------------------

__device__ __forceinline__ void async_copy16(const void* g, void* l) {
  __builtin_amdgcn_global_load_lds(
      (const __attribute__((address_space(1))) void*)g,
      (__attribute__((address_space(3))) void*)l, 16, 0, 0);
}

// LDS: 4 ring slots x 32KB. Slot = one kstep (32 K-cols): [A 256x32][B 256x32]
// bf16, 64B rows, chunk-XOR swizzle phys_chunk = logical ^ ((row>>1)&3)
// (measured 0 conflicts). Stage side applies the inverse via the per-lane
// GLOBAL source address (LDS dest stays linear for global_load_lds).

template<int SLOT>
__device__ __forceinline__ void stage_kstep(char* smem, int w,
                                            const unsigned short* sA,
                                            const unsigned short* sB,
                                            int koff) {
  char* base = smem + SLOT * 32768 + w * 1024;
  async_copy16(sA + koff,                base);
  async_copy16(sA + koff + 128 * IN_DIM, base + 8192);
  async_copy16(sB + koff,                base + 16384);
  async_copy16(sB + koff + 128 * IN_DIM, base + 16384 + 8192);
}

template<int SLOT>
__device__ __forceinline__ void read_frags(const char* smem, int aRd, int bRd,
                                           bf16x8* aR, bf16x8* bR) {
  const char* base = smem + SLOT * 32768;
#pragma unroll
  for (int i = 0; i < 4; ++i)
    bR[i] = *(const bf16x8*)(base + 16384 + bRd + i * 1024);
#pragma unroll
  for (int i = 0; i < 8; ++i)
    aR[i] = *(const bf16x8*)(base + aRd + i * 1024);
}

__device__ __forceinline__ void mfma_kstep(const bf16x8* aR, const bf16x8* bR,
                                           f32x4 (*acc)[4]) {
  __builtin_amdgcn_s_setprio(1);
#pragma unroll
  for (int mi = 0; mi < 8; ++mi)
#pragma unroll
    for (int ni = 0; ni < 4; ++ni)
      acc[mi][ni] = __builtin_amdgcn_mfma_f32_16x16x32_bf16(
          aR[mi], bR[ni], acc[mi][ni], 0, 0, 0);
  __builtin_amdgcn_s_setprio(0);
}

// body(s): vmcnt -> barrier -> stage(s+3) -> read(s+1)->nxt -> MFMA(s, cur)
template<int SRD, int SST, int VM, bool STG, bool RD>
__device__ __forceinline__ void body(char* smem, int w, int aRd, int bRd,
                                     const unsigned short* sA,
                                     const unsigned short* sB, int koff,
                                     bf16x8* aCur, bf16x8* bCur,
                                     bf16x8* aNxt, bf16x8* bNxt,
                                     f32x4 (*acc)[4]) {
  if (VM == 4) asm volatile("s_waitcnt vmcnt(4)" ::: "memory");
  if (VM == 0) asm volatile("s_waitcnt vmcnt(0)" ::: "memory");
  __builtin_amdgcn_s_barrier();
  if (STG) stage_kstep<SST>(smem, w, sA, sB, koff);
  if (RD) read_frags<SRD>(smem, aRd, bRd, aNxt, bNxt);
  mfma_kstep(aCur, bCur, acc);
}

__global__ __launch_bounds__(512, 2) void gemm_kernel(
    const unsigned short* __restrict__ xb,   // [8192][4096] bf16
    const unsigned short* __restrict__ rb,   // [4096][4096] bf16 (rows)
    const float* __restrict__ bias,          // [4096]
    float* __restrict__ out) {               // [8192][4096] fp32
  __shared__ __align__(16) char smem[4 * 32768];  // 128 KiB ring

  const int tid = threadIdx.x;
  const int w = tid >> 6, l = tid & 63;
  const int wr = w >> 2, wc = w & 3;       // 2 x 4 wave grid, wave owns 128x64

  // bijective XCD swizzle: 512 blocks = 8 XCDs x 64
  const int orig = blockIdx.x;
  const int wg = (orig & 7) * 64 + (orig >> 3);
  const int bm = (wg >> 4) * 256;          // 32 M-tiles
  const int bn = (wg & 15) * 256;          // 16 N-tiles

  // staging: thread t covers phys LDS bytes [t*16, t*16+16) of an 8KB chunk.
  // phys row r = 16w + (l>>2) (+128 second copy; (r>>1)&3 = (l>>3)&3 both);
  // phys chunk = l&3; stored logical chunk = (l&3) ^ ((l>>3)&3).
  const int sgr = w * 16 + (l >> 2);
  const int sgc = ((l & 3) ^ ((l >> 3) & 3)) << 3;
  const unsigned short* sA = xb + (size_t)(bm + sgr) * IN_DIM + sgc;
  const unsigned short* sB = rb + (size_t)(bn + sgr) * IN_DIM + sgc;

  // frag reads: row = 16-aligned base + (l&15), logical chunk (l>>4)
  //   -> phys chunk = (l>>4) ^ ((row>>1)&3) = (l>>4) ^ ((l>>1)&3)
  const int swz = ((l >> 4) ^ ((l >> 1) & 3)) << 4;
  const int aRd = (wr * 128 + (l & 15)) * 64 + swz;
  const int bRd = (wc * 64 + (l & 15)) * 64 + swz;

  f32x4 acc[8][4];
#pragma unroll
  for (int i = 0; i < 8; ++i)
#pragma unroll
    for (int j = 0; j < 4; ++j) acc[i][j] = (f32x4){0.f, 0.f, 0.f, 0.f};
  bf16x8 aR0[8], bR0[4], aR1[8], bR1[4];

  // ---- prologue: stage ksteps 0,1,2 into slots 0,1,2; load kstep0 regs
  stage_kstep<0>(smem, w, sA, sB, 0);
  stage_kstep<1>(smem, w, sA, sB, 32);
  stage_kstep<2>(smem, w, sA, sB, 64);
  asm volatile("s_waitcnt vmcnt(8)" ::: "memory");  // kstep0 landed
  __builtin_amdgcn_s_barrier();
  read_frags<0>(smem, aRd, bRd, aR0, bR0);

  // ---- main loop: ksteps 0..123, 4 per iteration (ring slot = s&3)
  for (int it = 0; it < 31; ++it) {
    body<1, 3, 4, true, true>(smem, w, aRd, bRd, sA, sB,  96, aR0, bR0, aR1, bR1, acc);
    body<2, 0, 4, true, true>(smem, w, aRd, bRd, sA, sB, 128, aR1, bR1, aR0, bR0, acc);
    body<3, 1, 4, true, true>(smem, w, aRd, bRd, sA, sB, 160, aR0, bR0, aR1, bR1, acc);
    body<0, 2, 4, true, true>(smem, w, aRd, bRd, sA, sB, 192, aR1, bR1, aR0, bR0, acc);
    sA += 128; sB += 128;
  }
  // ---- tail: ksteps 124..127 (sA at kstep 124)
  body<1, 3, 4, true,  true >(smem, w, aRd, bRd, sA, sB, 96, aR0, bR0, aR1, bR1, acc); // s=124, stage 127
  body<2, 0, 4, false, true >(smem, w, aRd, bRd, sA, sB, 0,  aR1, bR1, aR0, bR0, acc); // s=125
  body<3, 0, 0, false, true >(smem, w, aRd, bRd, sA, sB, 0,  aR0, bR0, aR1, bR1, acc); // s=126
  body<0, 0, -1, false, false>(smem, w, aRd, bRd, sA, sB, 0, aR1, bR1, aR0, bR0, acc); // s=127

  // ---- epilogue: C/D layout col=lane&15, row=(lane>>4)*4+reg (m89-verified)
#pragma unroll
  for (int mi = 0; mi < 8; ++mi) {
    const int row = bm + wr * 128 + mi * 16 + (l >> 4) * 4;
#pragma unroll
    for (int ni = 0; ni < 4; ++ni) {
      const int col = bn + wc * 64 + ni * 16 + (l & 15);
      const float bv = bias[col];
      float* po = out + (size_t)row * OUT_DIM + col;
#pragma unroll
      for (int r2 = 0; r2 < 4; ++r2)
        po[(size_t)r2 * OUT_DIM] = acc[mi][ni][r2] + bv;
    }
  }
}

// ---- host ---------------------------------------------------------------

extern "C" void kernel_launch(void* const* d_in, const int* in_sizes, int n_in,
                              void* d_out, int out_size, void* d_ws, size_t ws_size,
                              hipStream_t stream) {
  const float* x    = (const float*)d_in[0];
  const float* c    = (const float*)d_in[1];
  const float* bias = (const float*)d_in[2];
  float* out = (float*)d_out;

  const size_t xb_elems = (size_t)B_DIM * IN_DIM;
  const size_t rb_elems = (size_t)OUT_DIM * IN_DIM;
  if (ws_size < (xb_elems + rb_elems) * sizeof(unsigned short)) return;

  unsigned short* xb = (unsigned short*)d_ws;
  unsigned short* rb = xb + xb_elems;

  cvt_fused_kernel<<<XCHUNKS + RCHUNKS, 256, 0, stream>>>(x, c, xb, rb);

  const int grid = (B_DIM / 256) * (OUT_DIM / 256);  // 32*16 = 512
  gemm_kernel<<<grid, 512, 0, stream>>>(xb, rb, bias, out);
}

// Round 7
// 282.366 us; speedup vs baseline: 1.0514x; 1.0514x over previous
//
#include <hip/hip_runtime.h>
#include <hip/hip_bf16.h>
#include <stdint.h>

// CirculantLinear == dense GEMM: y[b,o] = sum_n x[b,n]*rows[o,n] + bias[o]
// where rows[o,n] = c[o, (4096-n) & 4095].
// M=8192 (B), N=4096 (OUT), K=4096 (IN). fp32 in/out, bf16 MFMA inside.
// R3: T2 swizzle XOR (row>>1)&3 -> conflicts 0. (248 us GEMM)
// R4: 32x32x16 -> regressed (conflicts back) -> reverted.
// R5: drop lgkm drain -> null (246 us). Phase = serial(LDS 576cy + MFMA 620cy).
// R6: reg double-buffer via swapped POINTER args -> scratch spill (rule #20
//     sibling): MfmaUtil*dur fell 4x. Reverted.
// R7: reg read-ahead with ALL-STATIC named frags (macros, no arrays):
//     phase p = stage + ds_read C(p+1) into idle set + MFMA C(p) from live
//     set + vmcnt(2)@odd phases + ONE barrier. LDS overlaps MFMA pipe.

#define B_DIM  8192
#define OUT_DIM 4096
#define IN_DIM  4096

typedef __attribute__((ext_vector_type(8))) short bf16x8;
typedef __attribute__((ext_vector_type(4))) float f32x4;
typedef __attribute__((ext_vector_type(8))) unsigned short u16x8;

__device__ __forceinline__ unsigned short f2bf(float f) {
  unsigned u = __float_as_uint(f);
  return (unsigned short)((u + 0x7fffu + ((u >> 16) & 1u)) >> 16);
}

// ---- fused conversion kernel --------------------------------------------

#define XCHUNKS (B_DIM * IN_DIM / 8 / 256)     // 16384 blocks for x
#define RCHUNKS (OUT_DIM * IN_DIM / 8 / 256)   // 8192 blocks for rows

__global__ void cvt_fused_kernel(const float* __restrict__ x,
                                 const float* __restrict__ c,
                                 unsigned short* __restrict__ xb,
                                 unsigned short* __restrict__ rb) {
  int b = blockIdx.x;
  if (b < XCHUNKS) {
    size_t i = ((size_t)b * 256 + threadIdx.x) * 8;
    const float4* p = (const float4*)(x + i);
    float4 a = p[0];
    float4 q = p[1];
    u16x8 o;
    o[0] = f2bf(a.x); o[1] = f2bf(a.y); o[2] = f2bf(a.z); o[3] = f2bf(a.w);
    o[4] = f2bf(q.x); o[5] = f2bf(q.y); o[6] = f2bf(q.z); o[7] = f2bf(q.w);
    *(u16x8*)(xb + i) = o;
  } else {
    int idx = (b - XCHUNKS) * 256 + threadIdx.x;
    int o  = idx >> 9;
    int n0 = (idx & 511) << 3;
    const float* crow = c + (size_t)o * IN_DIM;
    u16x8 v;
#pragma unroll
    for (int j = 0; j < 8; ++j) {
      int n = n0 + j;
      int s = (IN_DIM - n) & (IN_DIM - 1);
      v[j] = f2bf(crow[s]);
    }
    *(u16x8*)(rb + (size_t)o * IN_DIM + n0) = v;
  }
}

// ---- GEMM ---------------------------------------------------------------

__device__ __forceinline__ void async_copy16(const void* g, void* l) {
  __builtin_amdgcn_global_load_lds(
      (const __attribute__((address_space(1))) void*)g,
      (__attribute__((address_space(3))) void*)l, 16, 0, 0);
}

#define SMEM_BUF 65536
// Per buffer: [A kh0 16K][A kh1 16K][B kh0 16K][B kh1 16K]; khalf = row-major
// [256][32] bf16, 64B rows (4 16B chunks), chunk-XOR swizzle
// phys_chunk = logical ^ ((row>>1)&3)  (measured 0 conflicts). Stage side
// applies the inverse via the per-lane GLOBAL address (LDS dest linear).

#define STAGE(BUF, MAT, KK, srcp)                                            \
  async_copy16((srcp), smem + (BUF)*SMEM_BUF + (MAT)*32768 + (KK)*16384 +    \
                           w * 1024);                                        \
  async_copy16((srcp) + 128 * IN_DIM,                                        \
               smem + (BUF)*SMEM_BUF + (MAT)*32768 + (KK)*16384 + 8192 +     \
                   w * 1024)

#define LDSA(BUF, KK, MH, i)                                                 \
  (*(const bf16x8*)(smem + (BUF)*SMEM_BUF + (KK)*16384 + aRd +               \
                    ((MH)*4 + (i)) * 1024))
#define LDSB(BUF, KK, i)                                                     \
  (*(const bf16x8*)(smem + (BUF)*SMEM_BUF + 32768 + (KK)*16384 + bRd +       \
                    (i) * 1024))

#define READA(d, BUF, KK, MH)                                                \
  d##0 = LDSA(BUF, KK, MH, 0); d##1 = LDSA(BUF, KK, MH, 1);                  \
  d##2 = LDSA(BUF, KK, MH, 2); d##3 = LDSA(BUF, KK, MH, 3)
#define READB(d, BUF, KK)                                                    \
  d##0 = LDSB(BUF, KK, 0); d##1 = LDSB(BUF, KK, 1);                          \
  d##2 = LDSB(BUF, KK, 2); d##3 = LDSB(BUF, KK, 3)

#define MM(a, b, r, cc)                                                      \
  acc[r][cc] = __builtin_amdgcn_mfma_f32_16x16x32_bf16(a, b, acc[r][cc], 0, 0, 0)

#define MFMA16(a, b, MH)                                                     \
  __builtin_amdgcn_s_setprio(1);                                             \
  MM(a##0, b##0, (MH)*4+0, 0); MM(a##0, b##1, (MH)*4+0, 1);                  \
  MM(a##0, b##2, (MH)*4+0, 2); MM(a##0, b##3, (MH)*4+0, 3);                  \
  MM(a##1, b##0, (MH)*4+1, 0); MM(a##1, b##1, (MH)*4+1, 1);                  \
  MM(a##1, b##2, (MH)*4+1, 2); MM(a##1, b##3, (MH)*4+1, 3);                  \
  MM(a##2, b##0, (MH)*4+2, 0); MM(a##2, b##1, (MH)*4+2, 1);                  \
  MM(a##2, b##2, (MH)*4+2, 2); MM(a##2, b##3, (MH)*4+2, 3);                  \
  MM(a##3, b##0, (MH)*4+3, 0); MM(a##3, b##1, (MH)*4+3, 1);                  \
  MM(a##3, b##2, (MH)*4+3, 2); MM(a##3, b##3, (MH)*4+3, 3);                  \
  __builtin_amdgcn_s_setprio(0)

#define VMC(n) asm volatile("s_waitcnt vmcnt(" #n ")" ::: "memory")
#define BAR    __builtin_amdgcn_s_barrier()

__global__ __launch_bounds__(512, 2) void gemm_kernel(
    const unsigned short* __restrict__ xb,   // [8192][4096] bf16
    const unsigned short* __restrict__ rb,   // [4096][4096] bf16 (rows)
    const float* __restrict__ bias,          // [4096]
    float* __restrict__ out) {               // [8192][4096] fp32
  __shared__ __align__(16) char smem[2 * SMEM_BUF];  // 128 KiB

  const int tid = threadIdx.x;
  const int w = tid >> 6, l = tid & 63;
  const int wr = w >> 2, wc = w & 3;       // 2 x 4 wave grid, wave owns 128x64

  // bijective XCD swizzle: 512 blocks = 8 XCDs x 64
  const int orig = blockIdx.x;
  const int wg = (orig & 7) * 64 + (orig >> 3);
  const int bm = (wg >> 4) * 256;          // 32 M-tiles
  const int bn = (wg & 15) * 256;          // 16 N-tiles

  // staging: phys row r = 16w + (l>>2) (+128 2nd copy); phys chunk = l&3;
  // stored logical chunk = (l&3) ^ ((l>>3)&3)  -> pre-swizzled global col.
  const int sgr = w * 16 + (l >> 2);
  const int sgc = ((l & 3) ^ ((l >> 3) & 3)) << 3;
  const unsigned short* sA = xb + (size_t)(bm + sgr) * IN_DIM + sgc;
  const unsigned short* sB = rb + (size_t)(bn + sgr) * IN_DIM + sgc;

  // frag reads: row = 16-aligned base + (l&15), logical chunk (l>>4)
  //   -> phys chunk = (l>>4) ^ ((l>>1)&3)
  const int swz = ((l >> 4) ^ ((l >> 1) & 3)) << 4;
  const int aRd = (wr * 128 + (l & 15)) * 64 + swz;
  const int bRd = (wc * 64 + (l & 15)) * 64 + swz;

  f32x4 acc[8][4];
#pragma unroll
  for (int i = 0; i < 8; ++i)
#pragma unroll
    for (int j = 0; j < 4; ++j) acc[i][j] = (f32x4){0.f, 0.f, 0.f, 0.f};

  // static-named fragment double-buffer (no arrays -> guaranteed registers)
  bf16x8 aP0, aP1, aP2, aP3, aQ0, aQ1, aQ2, aQ3;
  bf16x8 bP0, bP1, bP2, bP3, bQ0, bQ1, bQ2, bQ3;

  // ---- prologue: stage K-tile 0 into buf0; read C1 (b0,k0,MH0)
  STAGE(0, 0, 0, sA);        // S1: A kh0
  STAGE(0, 1, 0, sB);        // S2: B kh0
  STAGE(0, 0, 1, sA + 32);   // S3: A kh1
  STAGE(0, 1, 1, sB + 32);   // S4: B kh1
  sA += 64; sB += 64;        // -> K-tile 1
  VMC(4);                    // S1,S2 landed
  BAR;
  READA(aP, 0, 0, 0);
  READB(bP, 0, 0);

  // ---- main loop: 31 iterations x 2 K-tiles (kt 0..61)
  for (int it = 0; it < 31; ++it) {
    // ph1: MFMA C1(b0,k0,MH0); read C2; stage b1.A.kh0
    STAGE(1, 0, 0, sA);
    READA(aQ, 0, 0, 1);
    MFMA16(aP, bP, 0);
    VMC(2); BAR;
    // ph2: MFMA C2(b0,k0,MH1); read C3; stage b1.B.kh0
    STAGE(1, 1, 0, sB);
    READA(aP, 0, 1, 0); READB(bQ, 0, 1);
    MFMA16(aQ, bP, 1);
    BAR;
    // ph3: MFMA C3(b0,k1,MH0); read C4; stage b1.A.kh1
    STAGE(1, 0, 1, sA + 32);
    READA(aQ, 0, 1, 1);
    MFMA16(aP, bQ, 0);
    VMC(2); BAR;
    // ph4: MFMA C4(b0,k1,MH1); read C5; stage b1.B.kh1
    STAGE(1, 1, 1, sB + 32);
    READA(aP, 1, 0, 0); READB(bP, 1, 0);
    MFMA16(aQ, bQ, 1);
    BAR;
    // ph5: MFMA C5(b1,k0,MH0); read C6; stage b0'.A.kh0
    STAGE(0, 0, 0, sA + 64);
    READA(aQ, 1, 0, 1);
    MFMA16(aP, bP, 0);
    VMC(2); BAR;
    // ph6: MFMA C6(b1,k0,MH1); read C7; stage b0'.B.kh0
    STAGE(0, 1, 0, sB + 64);
    READA(aP, 1, 1, 0); READB(bQ, 1, 1);
    MFMA16(aQ, bP, 1);
    BAR;
    // ph7: MFMA C7(b1,k1,MH0); read C8; stage b0'.A.kh1
    STAGE(0, 0, 1, sA + 96);
    READA(aQ, 1, 1, 1);
    MFMA16(aP, bQ, 0);
    VMC(2); BAR;
    // ph8: MFMA C8(b1,k1,MH1); read C1'; stage b0'.B.kh1
    STAGE(0, 1, 1, sB + 96);
    READA(aP, 0, 0, 0); READB(bP, 0, 0);
    MFMA16(aQ, bQ, 1);
    BAR;
    sA += 128; sB += 128;
  }

  // ---- final iteration: kt 62 (buf0) + kt 63 (buf1), no b0' staging
  STAGE(1, 0, 0, sA);
  READA(aQ, 0, 0, 1);
  MFMA16(aP, bP, 0);
  VMC(2); BAR;
  STAGE(1, 1, 0, sB);
  READA(aP, 0, 1, 0); READB(bQ, 0, 1);
  MFMA16(aQ, bP, 1);
  BAR;
  STAGE(1, 0, 1, sA + 32);
  READA(aQ, 0, 1, 1);
  MFMA16(aP, bQ, 0);
  VMC(2); BAR;
  STAGE(1, 1, 1, sB + 32);
  READA(aP, 1, 0, 0); READB(bP, 1, 0);
  MFMA16(aQ, bQ, 1);
  BAR;
  // ph5: drain remaining stages (ph3,ph4) before ph6 reads b1.k1
  READA(aQ, 1, 0, 1);
  MFMA16(aP, bP, 0);
  VMC(0); BAR;
  READA(aP, 1, 1, 0); READB(bQ, 1, 1);
  MFMA16(aQ, bP, 1);
  BAR;
  READA(aQ, 1, 1, 1);
  MFMA16(aP, bQ, 0);
  BAR;
  MFMA16(aQ, bQ, 1);

  // ---- epilogue: C/D layout col=lane&15, row=(lane>>4)*4+reg (m89-verified)
#pragma unroll
  for (int mi = 0; mi < 8; ++mi) {
    const int row = bm + wr * 128 + mi * 16 + (l >> 4) * 4;
#pragma unroll
    for (int ni = 0; ni < 4; ++ni) {
      const int col = bn + wc * 64 + ni * 16 + (l & 15);
      const float bv = bias[col];
      float* po = out + (size_t)row * OUT_DIM + col;
#pragma unroll
      for (int r2 = 0; r2 < 4; ++r2)
        po[(size_t)r2 * OUT_DIM] = acc[mi][ni][r2] + bv;
    }
  }
}

// ---- host ---------------------------------------------------------------

extern "C" void kernel_launch(void* const* d_in, const int* in_sizes, int n_in,
                              void* d_out, int out_size, void* d_ws, size_t ws_size,
                              hipStream_t stream) {
  const float* x    = (const float*)d_in[0];
  const float* c    = (const float*)d_in[1];
  const float* bias = (const float*)d_in[2];
  float* out = (float*)d_out;

  const size_t xb_elems = (size_t)B_DIM * IN_DIM;
  const size_t rb_elems = (size_t)OUT_DIM * IN_DIM;
  if (ws_size < (xb_elems + rb_elems) * sizeof(unsigned short)) return;

  unsigned short* xb = (unsigned short*)d_ws;
  unsigned short* rb = xb + xb_elems;

  cvt_fused_kernel<<<XCHUNKS + RCHUNKS, 256, 0, stream>>>(x, c, xb, rb);

  const int grid = (B_DIM / 256) * (OUT_DIM / 256);  // 32*16 = 512
  gemm_kernel<<<grid, 512, 0, stream>>>(xb, rb, bias, out);
}